// Round 7
// baseline (81.508 us; speedup 1.0000x reference)
//
#include <hip/hip_runtime.h>
#include <hip/hip_fp16.h>
#include <math.h>

#define NV 10475
#define NDS 2048
#define NHAND 1554
#define NHA 777
#define NCONTACT 300
#define NQ (NHAND + NDS)             // 3602 query rows
#define NVEC4 (NV / 4)               // 2618 float4 per row
#define FULL_ITERS 40                // 2618 = 40*64 + 58
#define LAST_LANES 58
#define TAIL0 (NVEC4 * 4)            // 10472
#define MASK_DW ((NV + 31) / 32)     // 328

#define THREADS 512                  // 8 waves, one query each
#define QPB 8
#define BLOCKS ((NQ + QPB - 1) / QPB)  // 451

// dynamic LDS layout (bytes)
#define OFF_SXY  0
#define OFF_SZ   41904                   // NV*4 -> pad16
#define OFF_CIDX (OFF_SZ + 20960)        // NV*2 -> pad16   = 62864
#define SMEM_TOTAL (OFF_CIDX + 1216)     // 300*4 -> pad16  = 64080

#define GEO_THRESH 0.3f
#define EXT_THRESH 0.02f
#define A1c 0.04f
#define A2c 0.04f
#define B1c 0.07f
#define B2c 0.06f
#define C1c 0.01f
#define C2c 0.01f
#define D1c 0.023f
#define D2c 0.02f
#define CONTACT_W 0.5f
#define INSIDE_W 0.5f
#define HAND_W 1.0f

__device__ __forceinline__ void upd(float g, float cx, float cy, float cz,
                                    float px, float py, float pz, float& best) {
    float dx = px - cx, dy = py - cy, dz = pz - cz;
    float d2 = fmaf(dx, dx, fmaf(dy, dy, dz * dz));
    best = fminf(best, (g < GEO_THRESH) ? INFINITY : d2);
}

// ---------------------------------------------------------------------------
// Fused kernel: per-block LDS staging of fp16-rounded vertices; one wave per
// query row with a UNIFORM 40-iteration unconditional-load main loop
// (unroll 8 -> deep MLP); gdi gathered post-scan from the L2-hot row; last
// block to finish runs the masked-mean finalize (agent-scope release/acquire).
// ---------------------------------------------------------------------------
__global__ __launch_bounds__(THREADS, 4)
void fused_kernel(const float* __restrict__ verts,
                  const float* __restrict__ geodist,
                  const int* __restrict__ hand_idx,
                  const int* __restrict__ ds,
                  const int* __restrict__ cidx,
                  const float* __restrict__ hw,
                  float* __restrict__ hand_min,
                  float* __restrict__ ds_min,
                  float* __restrict__ gdiq,
                  int* __restrict__ done,
                  float* __restrict__ out) {
    extern __shared__ __align__(16) char smem[];
    __half2* sxy = (__half2*)(smem + OFF_SXY);
    __half*  sz  = (__half*)(smem + OFF_SZ);
    int* cidxs   = (int*)(smem + OFF_CIDX);
    __shared__ int lflag;

    const int tid = threadIdx.x;
    const int lane = tid & 63;
    const int wave = tid >> 6;

    // stage fp16-rounded vertices + contact index list into LDS
    for (int n = tid; n < NV; n += THREADS) {
        sxy[n] = __halves2half2(__float2half(verts[3 * n + 0]),
                                __float2half(verts[3 * n + 1]));
        sz[n] = __float2half(verts[3 * n + 2]);
    }
    if (tid < NCONTACT) cidxs[tid] = cidx[tid];
    __syncthreads();

    const int gq = blockIdx.x * QPB + wave;
    if (gq < NQ) {
        const bool is_ds = (gq >= NHAND);
        const int i_out = is_ds ? (gq - NHAND) : gq;
        const int q = is_ds ? ds[i_out] : hand_idx[gq];
        const float* __restrict__ grow = geodist + (size_t)q * NV;

        const float2 pxy = __half22float2(sxy[q]);
        const float px = pxy.x, py = pxy.y;
        const float pz = __half2float(sz[q]);

        const float4* __restrict__ g4p = (const float4*)grow;  // 4B-align OK
        const uint4* __restrict__ sxy4 = (const uint4*)sxy;
        const uint2* __restrict__ sz2 = (const uint2*)sz;

        float best = INFINITY, gb = INFINITY;

        // uniform trip count: every lane does 40 unconditional iterations
        #pragma unroll 8
        for (int jj = 0; jj < FULL_ITERS; ++jj) {
            const int j = jj * 64 + lane;
            const float4 g4 = g4p[j];
            const uint4 xy = sxy4[j];
            const uint2 zz = sz2[j];
            const float2 c0 = __half22float2(*(const __half2*)&xy.x);
            const float2 c1 = __half22float2(*(const __half2*)&xy.y);
            const float2 c2 = __half22float2(*(const __half2*)&xy.z);
            const float2 c3 = __half22float2(*(const __half2*)&xy.w);
            const float2 z01 = __half22float2(*(const __half2*)&zz.x);
            const float2 z23 = __half22float2(*(const __half2*)&zz.y);
            upd(g4.x, c0.x, c0.y, z01.x, px, py, pz, best);
            upd(g4.y, c1.x, c1.y, z01.y, px, py, pz, best);
            upd(g4.z, c2.x, c2.y, z23.x, px, py, pz, best);
            upd(g4.w, c3.x, c3.y, z23.y, px, py, pz, best);
        }
        if (lane < LAST_LANES) {          // straggler float4 iteration
            const int j = FULL_ITERS * 64 + lane;
            const float4 g4 = g4p[j];
            const uint4 xy = sxy4[j];
            const uint2 zz = sz2[j];
            const float2 c0 = __half22float2(*(const __half2*)&xy.x);
            const float2 c1 = __half22float2(*(const __half2*)&xy.y);
            const float2 c2 = __half22float2(*(const __half2*)&xy.z);
            const float2 c3 = __half22float2(*(const __half2*)&xy.w);
            const float2 z01 = __half22float2(*(const __half2*)&zz.x);
            const float2 z23 = __half22float2(*(const __half2*)&zz.y);
            upd(g4.x, c0.x, c0.y, z01.x, px, py, pz, best);
            upd(g4.y, c1.x, c1.y, z01.y, px, py, pz, best);
            upd(g4.z, c2.x, c2.y, z23.x, px, py, pz, best);
            upd(g4.w, c3.x, c3.y, z23.y, px, py, pz, best);
        }
        if (lane < NV - TAIL0) {          // 3 tail candidates
            const int n = TAIL0 + lane;
            const float2 c = __half22float2(sxy[n]);
            upd(grow[n], c.x, c.y, __half2float(sz[n]), px, py, pz, best);
        }
        if (is_ds) {   // gdi: gather 300 contact columns from the L2-hot row
            for (int k = lane; k < NCONTACT; k += 64)
                gb = fminf(gb, grow[cidxs[k]]);
        }

        #pragma unroll
        for (int off = 32; off > 0; off >>= 1) {
            best = fminf(best, __shfl_down(best, off));
            gb = fminf(gb, __shfl_down(gb, off));
        }
        if (lane == 0) {
            const float d = sqrtf(best + 1e-12f);
            if (is_ds) {
                ds_min[i_out] = d;
                gdiq[i_out] = gb;
            } else {
                hand_min[gq] = d;
            }
        }
    }

    // ---- last-block election ----
    if (tid == 0) {
        __threadfence();  // release our outputs device-wide
        const int old = __hip_atomic_fetch_add(done, 1, __ATOMIC_ACQ_REL,
                                               __HIP_MEMORY_SCOPE_AGENT);
        lflag = (old == (int)gridDim.x - 1) ? 1 : 0;
    }
    __syncthreads();
    if (!lflag) return;
    __builtin_amdgcn_fence(__ATOMIC_ACQUIRE, "agent");

    // ---- finalize (last block only); reuse LDS ----
    unsigned int* imask = (unsigned int*)smem;           // 1312 B
    float (*red)[12] = (float (*)[12])(smem + 4096);     // 8x12 floats

    for (int i = tid; i < MASK_DW; i += THREADS) imask[i] = 0u;
    __syncthreads();
    for (int i = tid; i < NDS; i += THREADS) {
        if (!(ds_min[i] > EXT_THRESH)) {
            const int v = ds[i];
            atomicOr(&imask[v >> 5], 1u << (v & 31));
        }
    }
    __syncthreads();

    float acc[12];
    #pragma unroll
    for (int k = 0; k < 12; ++k) acc[k] = 0.0f;

    for (int i = tid; i < NDS; i += THREADS) {
        const float m = ds_min[i];
        const int v = ds[i];
        const bool ins = (imask[v >> 5] >> (v & 31)) & 1u;
        if (!ins) {
            const float w = 1.0f / (5.0f * gdiq[i] + 1.0f);
            acc[0] += A1c * w * tanhf(m / A2c);
            acc[1] += 1.0f;
        } else {
            acc[2] += B1c * tanhf(m / B2c);
            acc[3] += 1.0f;
        }
    }
    for (int h = tid; h < NHAND; h += THREADS) {
        const float m = hand_min[h];
        const int v = hand_idx[h];
        const bool ins = (imask[v >> 5] >> (v & 31)) & 1u;
        const float w = -0.1f * hw[h] + 1.0f;
        const float o = w * C1c * tanhf(m / C2c);
        const float ii = D1c * tanhf(m / D2c);
        if (h < NHA) {
            if (!ins) { acc[4] += o;  acc[5] += 1.0f; }
            else      { acc[8] += ii; acc[9] += 1.0f; }
        } else {
            if (!ins) { acc[6]  += o;  acc[7]  += 1.0f; }
            else      { acc[10] += ii; acc[11] += 1.0f; }
        }
    }

    #pragma unroll
    for (int k = 0; k < 12; ++k) {
        float v = acc[k];
        #pragma unroll
        for (int off = 32; off > 0; off >>= 1)
            v += __shfl_down(v, off);
        acc[k] = v;
    }
    if (lane == 0) {
        #pragma unroll
        for (int k = 0; k < 12; ++k) red[wave][k] = acc[k];
    }
    __syncthreads();
    if (tid == 0) {
        float t[12];
        #pragma unroll
        for (int k = 0; k < 12; ++k) {
            float s = red[0][k];
            #pragma unroll
            for (int w = 1; w < THREADS / 64; ++w) s += red[w][k];
            t[k] = s;
        }
        const float contactloss = CONTACT_W * (t[0] / fmaxf(t[1], 1.0f));
        const float insideloss  = INSIDE_W  * (t[2] / fmaxf(t[3], 1.0f));
        const float hand_out = t[4] / fmaxf(t[5], 1.0f) + t[6]  / fmaxf(t[7], 1.0f);
        const float hand_in  = t[8] / fmaxf(t[9], 1.0f) + t[10] / fmaxf(t[11], 1.0f);
        out[0] = contactloss + insideloss + HAND_W * (hand_out + hand_in);
    }
}

extern "C" void kernel_launch(void* const* d_in, const int* in_sizes, int n_in,
                              void* d_out, int out_size, void* d_ws, size_t ws_size,
                              hipStream_t stream) {
    const float* vertices = (const float*)d_in[0];  // [1,NV,3]
    const float* geodist  = (const float*)d_in[1];  // [NV,NV]
    const float* hand_w   = (const float*)d_in[2];  // [NHAND]
    const int*   ds       = (const int*)d_in[3];    // [NDS]
    const int*   hand_idx = (const int*)d_in[4];    // [NHAND]
    const int*   cidx     = (const int*)d_in[5];    // [NCONTACT]
    float* out = (float*)d_out;

    char* p = (char*)d_ws;
    float* hand_min = (float*)p;  p += ((NHAND * 4 + 15) & ~15);
    float* ds_min = (float*)p;    p += ((NDS * 4 + 15) & ~15);
    float* gdiq = (float*)p;      p += ((NDS * 4 + 15) & ~15);
    int* done = (int*)p;          p += 16;

    // d_ws is poisoned 0xAA before timing -> zero the counter every call
    hipMemsetAsync(done, 0, sizeof(int), stream);

    fused_kernel<<<BLOCKS, THREADS, SMEM_TOTAL, stream>>>(
        vertices, geodist, hand_idx, ds, cidx, hand_w,
        hand_min, ds_min, gdiq, done, out);
}

// Round 8
// 50.254 us; speedup vs baseline: 1.6219x; 1.6219x over previous
//
#include <hip/hip_runtime.h>
#include <hip/hip_fp16.h>
#include <math.h>

#define NV 10475
#define NDS 2048
#define NHAND 1554
#define NHA 777
#define NCONTACT 300
#define NQ (NHAND + NDS)             // 3602 query rows
#define NVEC4 (NV / 4)               // 2618 float4 per row
#define TAIL0 (NVEC4 * 4)            // 10472
#define MASK_DW ((NV + 31) / 32)     // 328 dwords of bitmask

#define THREADS 512
#define BLOCKS ((NQ + 7) / 8)        // 451 blocks * 8 waves = 3608 >= NQ

// dynamic LDS layout (bytes)
#define SXY_BYTES ((NV * 4 + 15) & ~15)   // 41904
#define SZ_BYTES  ((NV * 2 + 15) & ~15)   // 20960
#define SMEM_BYTES (SXY_BYTES + SZ_BYTES) // 62864 (< 64 KB)

#define GEO_THRESH 0.3f
#define EXT_THRESH 0.02f
#define A1c 0.04f
#define A2c 0.04f
#define B1c 0.07f
#define B2c 0.06f
#define C1c 0.01f
#define C2c 0.01f
#define D1c 0.023f
#define D2c 0.02f
#define CONTACT_W 0.5f
#define INSIDE_W 0.5f
#define HAND_W 1.0f

__device__ __forceinline__ void upd(float g, float cx, float cy, float cz,
                                    float px, float py, float pz, float& best) {
    float dx = px - cx, dy = py - cy, dz = pz - cz;
    float d2 = fmaf(dx, dx, fmaf(dy, dy, dz * dz));
    best = fminf(best, (g < GEO_THRESH) ? INFINITY : d2);
}

// ---------------------------------------------------------------------------
// Scan kernel: one wave per query row. Each block self-stages fp16-rounded
// vertex coords into LDS (packed half2 xy + half z; global row stream is
// unaligned-float4 so candidate index n = 4j exactly -> aligned LDS b128/b64
// reads). ds rows also accumulate gdi = min over contact columns via an LDS
// bitmask folded into the same streamed row (no extra traffic).
// ---------------------------------------------------------------------------
__global__ __launch_bounds__(THREADS, 4)
void scan_kernel(const float* __restrict__ verts,
                 const float* __restrict__ geodist,
                 const int* __restrict__ hand_idx,
                 const int* __restrict__ ds,
                 const int* __restrict__ cidx,
                 float* __restrict__ hand_min,
                 float* __restrict__ ds_min,
                 float* __restrict__ gdiq) {
    extern __shared__ __align__(16) char smem[];
    __half2* sxy = (__half2*)smem;                 // [NV]
    __half*  sz  = (__half*)(smem + SXY_BYTES);    // [NV]
    __shared__ unsigned int cmask[MASK_DW];

    const int tid = threadIdx.x;
    const int lane = tid & 63;
    const int wave = tid >> 6;

    // phase 1: zero mask + convert vertices (fp16 round) into LDS
    for (int i = tid; i < MASK_DW; i += THREADS) cmask[i] = 0u;
    for (int n = tid; n < NV; n += THREADS) {
        sxy[n] = __halves2half2(__float2half(verts[3 * n + 0]),
                                __float2half(verts[3 * n + 1]));
        sz[n] = __float2half(verts[3 * n + 2]);
    }
    __syncthreads();
    // phase 2: set contact-column bits
    if (tid < NCONTACT) {
        const int c = cidx[tid];
        atomicOr(&cmask[c >> 5], 1u << (c & 31));
    }
    __syncthreads();

    const int gw = blockIdx.x * (THREADS / 64) + wave;
    if (gw >= NQ) return;

    const bool is_ds = (gw >= NHAND);
    const int i_out = is_ds ? (gw - NHAND) : gw;
    const int q = is_ds ? ds[i_out] : hand_idx[gw];
    const float* __restrict__ grow = geodist + (size_t)q * NV;

    const float2 pxy = __half22float2(sxy[q]);
    const float px = pxy.x, py = pxy.y;
    const float pz = __half2float(sz[q]);

    const float4* __restrict__ g4p = (const float4*)grow;   // 4B-aligned OK on gfx950
    const uint4* __restrict__ sxy4 = (const uint4*)sxy;
    const uint2* __restrict__ sz2 = (const uint2*)sz;

    float best = INFINITY;
    float gb = INFINITY;

    if (is_ds) {
        #pragma unroll 8
        for (int j = lane; j < NVEC4; j += 64) {
            const float4 g4 = g4p[j];
            const uint4 xy = sxy4[j];
            const uint2 zz = sz2[j];
            const unsigned int mb = cmask[j >> 3] >> ((j & 7) * 4);
            const float2 c0 = __half22float2(*(const __half2*)&xy.x);
            const float2 c1 = __half22float2(*(const __half2*)&xy.y);
            const float2 c2 = __half22float2(*(const __half2*)&xy.z);
            const float2 c3 = __half22float2(*(const __half2*)&xy.w);
            const float2 z01 = __half22float2(*(const __half2*)&zz.x);
            const float2 z23 = __half22float2(*(const __half2*)&zz.y);
            upd(g4.x, c0.x, c0.y, z01.x, px, py, pz, best);
            upd(g4.y, c1.x, c1.y, z01.y, px, py, pz, best);
            upd(g4.z, c2.x, c2.y, z23.x, px, py, pz, best);
            upd(g4.w, c3.x, c3.y, z23.y, px, py, pz, best);
            gb = fminf(gb, (mb & 1u) ? g4.x : INFINITY);
            gb = fminf(gb, (mb & 2u) ? g4.y : INFINITY);
            gb = fminf(gb, (mb & 4u) ? g4.z : INFINITY);
            gb = fminf(gb, (mb & 8u) ? g4.w : INFINITY);
        }
    } else {
        #pragma unroll 8
        for (int j = lane; j < NVEC4; j += 64) {
            const float4 g4 = g4p[j];
            const uint4 xy = sxy4[j];
            const uint2 zz = sz2[j];
            const float2 c0 = __half22float2(*(const __half2*)&xy.x);
            const float2 c1 = __half22float2(*(const __half2*)&xy.y);
            const float2 c2 = __half22float2(*(const __half2*)&xy.z);
            const float2 c3 = __half22float2(*(const __half2*)&xy.w);
            const float2 z01 = __half22float2(*(const __half2*)&zz.x);
            const float2 z23 = __half22float2(*(const __half2*)&zz.y);
            upd(g4.x, c0.x, c0.y, z01.x, px, py, pz, best);
            upd(g4.y, c1.x, c1.y, z01.y, px, py, pz, best);
            upd(g4.z, c2.x, c2.y, z23.x, px, py, pz, best);
            upd(g4.w, c3.x, c3.y, z23.y, px, py, pz, best);
        }
    }

    if (lane < NV - TAIL0) {   // 3 tail candidates
        const int n = TAIL0 + lane;
        const float g = grow[n];
        const float2 c = __half22float2(sxy[n]);
        const float zc = __half2float(sz[n]);
        upd(g, c.x, c.y, zc, px, py, pz, best);
        if (is_ds) {
            const unsigned int bit = (cmask[n >> 5] >> (n & 31)) & 1u;
            gb = fminf(gb, bit ? g : INFINITY);
        }
    }

    #pragma unroll
    for (int off = 32; off > 0; off >>= 1) {
        best = fminf(best, __shfl_down(best, off));
        gb = fminf(gb, __shfl_down(gb, off));
    }

    if (lane == 0) {
        const float d = sqrtf(best + 1e-12f);
        if (is_ds) {
            ds_min[i_out] = d;
            gdiq[i_out] = gb;
        } else {
            hand_min[gw] = d;
        }
    }
}

// ---------------------------------------------------------------------------
// Finalize: single block. Builds the inside-vertex bitmask in LDS (exactly
// the reference's scatter-max over ds, duplicate-safe), then all masked means.
// ---------------------------------------------------------------------------
__global__ void finalize_kernel(const float* __restrict__ ds_min,
                                const float* __restrict__ gdiq,
                                const int* __restrict__ ds,
                                const float* __restrict__ hand_min,
                                const float* __restrict__ hw,
                                const int* __restrict__ hand_idx,
                                float* __restrict__ out) {
    __shared__ unsigned int imask[MASK_DW];
    const int tid = threadIdx.x;
    const int nthr = blockDim.x;

    for (int i = tid; i < MASK_DW; i += nthr) imask[i] = 0u;
    __syncthreads();
    for (int i = tid; i < NDS; i += nthr) {
        if (!(ds_min[i] > EXT_THRESH)) {
            const int v = ds[i];
            atomicOr(&imask[v >> 5], 1u << (v & 31));
        }
    }
    __syncthreads();

    float acc[12];
    #pragma unroll
    for (int k = 0; k < 12; ++k) acc[k] = 0.0f;

    for (int i = tid; i < NDS; i += nthr) {
        const float m = ds_min[i];
        const int v = ds[i];
        const bool ins = (imask[v >> 5] >> (v & 31)) & 1u;
        if (!ins) {
            const float w = 1.0f / (5.0f * gdiq[i] + 1.0f);
            acc[0] += A1c * w * tanhf(m / A2c);
            acc[1] += 1.0f;
        } else {
            acc[2] += B1c * tanhf(m / B2c);
            acc[3] += 1.0f;
        }
    }

    for (int h = tid; h < NHAND; h += nthr) {
        const float m = hand_min[h];
        const int v = hand_idx[h];
        const bool ins = (imask[v >> 5] >> (v & 31)) & 1u;
        const float w = -0.1f * hw[h] + 1.0f;
        const float o = w * C1c * tanhf(m / C2c);
        const float ii = D1c * tanhf(m / D2c);
        if (h < NHA) {
            if (!ins) { acc[4] += o;  acc[5] += 1.0f; }
            else      { acc[8] += ii; acc[9] += 1.0f; }
        } else {
            if (!ins) { acc[6]  += o;  acc[7]  += 1.0f; }
            else      { acc[10] += ii; acc[11] += 1.0f; }
        }
    }

    __shared__ float red[16][12];
    const int lane = tid & 63;
    const int wave = tid >> 6;
    #pragma unroll
    for (int k = 0; k < 12; ++k) {
        float v = acc[k];
        #pragma unroll
        for (int off = 32; off > 0; off >>= 1)
            v += __shfl_down(v, off);
        acc[k] = v;
    }
    if (lane == 0) {
        #pragma unroll
        for (int k = 0; k < 12; ++k) red[wave][k] = acc[k];
    }
    __syncthreads();
    if (tid == 0) {
        float t[12];
        const int nw = nthr >> 6;
        #pragma unroll
        for (int k = 0; k < 12; ++k) {
            float s = red[0][k];
            for (int w = 1; w < nw; ++w) s += red[w][k];
            t[k] = s;
        }
        const float contactloss = CONTACT_W * (t[0] / fmaxf(t[1], 1.0f));
        const float insideloss  = INSIDE_W  * (t[2] / fmaxf(t[3], 1.0f));
        const float hand_out = t[4] / fmaxf(t[5], 1.0f) + t[6]  / fmaxf(t[7], 1.0f);
        const float hand_in  = t[8] / fmaxf(t[9], 1.0f) + t[10] / fmaxf(t[11], 1.0f);
        out[0] = contactloss + insideloss + HAND_W * (hand_out + hand_in);
    }
}

extern "C" void kernel_launch(void* const* d_in, const int* in_sizes, int n_in,
                              void* d_out, int out_size, void* d_ws, size_t ws_size,
                              hipStream_t stream) {
    const float* vertices = (const float*)d_in[0];  // [1,NV,3]
    const float* geodist  = (const float*)d_in[1];  // [NV,NV]
    const float* hand_w   = (const float*)d_in[2];  // [NHAND]
    const int*   ds       = (const int*)d_in[3];    // [NDS]
    const int*   hand_idx = (const int*)d_in[4];    // [NHAND]
    const int*   cidx     = (const int*)d_in[5];    // [NCONTACT]
    float* out = (float*)d_out;

    char* p = (char*)d_ws;
    float* hand_min = (float*)p;  p += ((NHAND * 4 + 15) & ~15);
    float* ds_min = (float*)p;    p += ((NDS * 4 + 15) & ~15);
    float* gdiq = (float*)p;      p += ((NDS * 4 + 15) & ~15);

    scan_kernel<<<BLOCKS, THREADS, SMEM_BYTES, stream>>>(
        vertices, geodist, hand_idx, ds, cidx, hand_min, ds_min, gdiq);

    finalize_kernel<<<1, 1024, 0, stream>>>(ds_min, gdiq, ds, hand_min,
                                            hand_w, hand_idx, out);
}

// Round 9
// 49.178 us; speedup vs baseline: 1.6574x; 1.0219x over previous
//
#include <hip/hip_runtime.h>
#include <hip/hip_fp16.h>
#include <math.h>

#define NV 10475
#define NDS 2048
#define NHAND 1554
#define NHA 777
#define NCONTACT 300
#define NQ (NHAND + NDS)             // 3602 query rows
#define NVEC4 (NV / 4)               // 2618 float4 per row
#define FULL_ITERS 40                // uniform per-lane iterations (40*64=2560)
#define STRAG_LANES 58               // 2618-2560: lanes with a 41st float4
#define TAIL0 (NVEC4 * 4)            // 10472
#define MASK_DW ((NV + 31) / 32)     // 328 dwords of bitmask

#define THREADS 512
#define BLOCKS ((NQ + 7) / 8)        // 451 blocks * 8 waves = 3608 >= NQ
#define PFD 8                        // global prefetch depth (8 float4 in flight)

// dynamic LDS layout (bytes)
#define SXY_BYTES ((NV * 4 + 15) & ~15)   // 41904
#define SZ_BYTES  ((NV * 2 + 15) & ~15)   // 20960
#define SMEM_BYTES (SXY_BYTES + SZ_BYTES) // 62864 (< 64 KB)

#define GEO_THRESH 0.3f
#define EXT_THRESH 0.02f
#define A1c 0.04f
#define A2c 0.04f
#define B1c 0.07f
#define B2c 0.06f
#define C1c 0.01f
#define C2c 0.01f
#define D1c 0.023f
#define D2c 0.02f
#define CONTACT_W 0.5f
#define INSIDE_W 0.5f
#define HAND_W 1.0f

__device__ __forceinline__ void upd(float g, float cx, float cy, float cz,
                                    float px, float py, float pz, float& best) {
    float dx = px - cx, dy = py - cy, dz = pz - cz;
    float d2 = fmaf(dx, dx, fmaf(dy, dy, dz * dz));
    best = fminf(best, (g < GEO_THRESH) ? INFINITY : d2);
}

// process one float4 group (4 candidates) at float4-index j
template <bool IS_DS>
__device__ __forceinline__ void proc4(const float4 g4, const int j,
                                      const uint4* __restrict__ sxy4,
                                      const uint2* __restrict__ sz2,
                                      const unsigned int* __restrict__ cmask,
                                      const float px, const float py, const float pz,
                                      float& best, float& gb) {
    const uint4 xy = sxy4[j];
    const uint2 zz = sz2[j];
    const float2 c0 = __half22float2(*(const __half2*)&xy.x);
    const float2 c1 = __half22float2(*(const __half2*)&xy.y);
    const float2 c2 = __half22float2(*(const __half2*)&xy.z);
    const float2 c3 = __half22float2(*(const __half2*)&xy.w);
    const float2 z01 = __half22float2(*(const __half2*)&zz.x);
    const float2 z23 = __half22float2(*(const __half2*)&zz.y);
    upd(g4.x, c0.x, c0.y, z01.x, px, py, pz, best);
    upd(g4.y, c1.x, c1.y, z01.y, px, py, pz, best);
    upd(g4.z, c2.x, c2.y, z23.x, px, py, pz, best);
    upd(g4.w, c3.x, c3.y, z23.y, px, py, pz, best);
    if (IS_DS) {
        const unsigned int mb = cmask[j >> 3] >> ((j & 7) * 4);
        gb = fminf(gb, (mb & 1u) ? g4.x : INFINITY);
        gb = fminf(gb, (mb & 2u) ? g4.y : INFINITY);
        gb = fminf(gb, (mb & 4u) ? g4.z : INFINITY);
        gb = fminf(gb, (mb & 8u) ? g4.w : INFINITY);
    }
}

// full row scan with an 8-deep rotating register prefetch of the GLOBAL row
// loads only (LDS reads + cvts issued just-in-time at consume).
template <bool IS_DS>
__device__ __forceinline__ void scan_row(const float4* __restrict__ g4p,
                                         const float* __restrict__ grow,
                                         const uint4* __restrict__ sxy4,
                                         const uint2* __restrict__ sz2,
                                         const __half2* __restrict__ sxy,
                                         const __half* __restrict__ sz,
                                         const unsigned int* __restrict__ cmask,
                                         const int lane,
                                         const float px, const float py, const float pz,
                                         float& best, float& gb) {
    float4 buf[PFD];
    #pragma unroll
    for (int k = 0; k < PFD; ++k) buf[k] = g4p[k * 64 + lane];

    #pragma unroll 1   // keep the rotation: exactly PFD loads in flight
    for (int jj = 0; jj < FULL_ITERS - PFD; jj += PFD) {
        #pragma unroll
        for (int k = 0; k < PFD; ++k) {
            const int j = (jj + k) * 64 + lane;
            proc4<IS_DS>(buf[k], j, sxy4, sz2, cmask, px, py, pz, best, gb);
            buf[k] = g4p[j + PFD * 64];
        }
    }
    #pragma unroll
    for (int k = 0; k < PFD; ++k) {   // drain: indices 32..39
        const int j = (FULL_ITERS - PFD + k) * 64 + lane;
        proc4<IS_DS>(buf[k], j, sxy4, sz2, cmask, px, py, pz, best, gb);
    }

    if (lane < STRAG_LANES) {         // 41st float4 for low lanes
        const int j = FULL_ITERS * 64 + lane;
        proc4<IS_DS>(g4p[j], j, sxy4, sz2, cmask, px, py, pz, best, gb);
    }
    if (lane < NV - TAIL0) {          // 3 scalar tail candidates
        const int n = TAIL0 + lane;
        const float g = grow[n];
        const float2 c = __half22float2(sxy[n]);
        upd(g, c.x, c.y, __half2float(sz[n]), px, py, pz, best);
        if (IS_DS) {
            const unsigned int bit = (cmask[n >> 5] >> (n & 31)) & 1u;
            gb = fminf(gb, bit ? g : INFINITY);
        }
    }
}

// ---------------------------------------------------------------------------
// Scan kernel: one wave per query row; per-block LDS staging of fp16-rounded
// vertices; in-loop bitmask gdi for ds rows.
// ---------------------------------------------------------------------------
__global__ __launch_bounds__(THREADS, 4)
void scan_kernel(const float* __restrict__ verts,
                 const float* __restrict__ geodist,
                 const int* __restrict__ hand_idx,
                 const int* __restrict__ ds,
                 const int* __restrict__ cidx,
                 float* __restrict__ hand_min,
                 float* __restrict__ ds_min,
                 float* __restrict__ gdiq) {
    extern __shared__ __align__(16) char smem[];
    __half2* sxy = (__half2*)smem;                 // [NV]
    __half*  sz  = (__half*)(smem + SXY_BYTES);    // [NV]
    __shared__ unsigned int cmask[MASK_DW];

    const int tid = threadIdx.x;
    const int lane = tid & 63;
    const int wave = tid >> 6;

    for (int i = tid; i < MASK_DW; i += THREADS) cmask[i] = 0u;
    for (int n = tid; n < NV; n += THREADS) {
        sxy[n] = __halves2half2(__float2half(verts[3 * n + 0]),
                                __float2half(verts[3 * n + 1]));
        sz[n] = __float2half(verts[3 * n + 2]);
    }
    __syncthreads();
    if (tid < NCONTACT) {
        const int c = cidx[tid];
        atomicOr(&cmask[c >> 5], 1u << (c & 31));
    }
    __syncthreads();

    const int gw = blockIdx.x * (THREADS / 64) + wave;
    if (gw >= NQ) return;

    const bool is_ds = (gw >= NHAND);
    const int i_out = is_ds ? (gw - NHAND) : gw;
    const int q = is_ds ? ds[i_out] : hand_idx[gw];
    const float* __restrict__ grow = geodist + (size_t)q * NV;

    const float2 pxy = __half22float2(sxy[q]);
    const float px = pxy.x, py = pxy.y;
    const float pz = __half2float(sz[q]);

    const float4* __restrict__ g4p = (const float4*)grow;   // 4B-aligned OK
    const uint4* __restrict__ sxy4 = (const uint4*)sxy;
    const uint2* __restrict__ sz2 = (const uint2*)sz;

    float best = INFINITY;
    float gb = INFINITY;

    if (is_ds) {
        scan_row<true>(g4p, grow, sxy4, sz2, sxy, sz, cmask, lane,
                       px, py, pz, best, gb);
    } else {
        scan_row<false>(g4p, grow, sxy4, sz2, sxy, sz, cmask, lane,
                        px, py, pz, best, gb);
    }

    #pragma unroll
    for (int off = 32; off > 0; off >>= 1) {
        best = fminf(best, __shfl_down(best, off));
        gb = fminf(gb, __shfl_down(gb, off));
    }

    if (lane == 0) {
        const float d = sqrtf(best + 1e-12f);
        if (is_ds) {
            ds_min[i_out] = d;
            gdiq[i_out] = gb;
        } else {
            hand_min[gw] = d;
        }
    }
}

// ---------------------------------------------------------------------------
// Finalize: single block. Builds the inside-vertex bitmask in LDS, then all
// masked means -> scalar loss.
// ---------------------------------------------------------------------------
__global__ void finalize_kernel(const float* __restrict__ ds_min,
                                const float* __restrict__ gdiq,
                                const int* __restrict__ ds,
                                const float* __restrict__ hand_min,
                                const float* __restrict__ hw,
                                const int* __restrict__ hand_idx,
                                float* __restrict__ out) {
    __shared__ unsigned int imask[MASK_DW];
    const int tid = threadIdx.x;
    const int nthr = blockDim.x;

    for (int i = tid; i < MASK_DW; i += nthr) imask[i] = 0u;
    __syncthreads();
    for (int i = tid; i < NDS; i += nthr) {
        if (!(ds_min[i] > EXT_THRESH)) {
            const int v = ds[i];
            atomicOr(&imask[v >> 5], 1u << (v & 31));
        }
    }
    __syncthreads();

    float acc[12];
    #pragma unroll
    for (int k = 0; k < 12; ++k) acc[k] = 0.0f;

    for (int i = tid; i < NDS; i += nthr) {
        const float m = ds_min[i];
        const int v = ds[i];
        const bool ins = (imask[v >> 5] >> (v & 31)) & 1u;
        if (!ins) {
            const float w = 1.0f / (5.0f * gdiq[i] + 1.0f);
            acc[0] += A1c * w * tanhf(m / A2c);
            acc[1] += 1.0f;
        } else {
            acc[2] += B1c * tanhf(m / B2c);
            acc[3] += 1.0f;
        }
    }

    for (int h = tid; h < NHAND; h += nthr) {
        const float m = hand_min[h];
        const int v = hand_idx[h];
        const bool ins = (imask[v >> 5] >> (v & 31)) & 1u;
        const float w = -0.1f * hw[h] + 1.0f;
        const float o = w * C1c * tanhf(m / C2c);
        const float ii = D1c * tanhf(m / D2c);
        if (h < NHA) {
            if (!ins) { acc[4] += o;  acc[5] += 1.0f; }
            else      { acc[8] += ii; acc[9] += 1.0f; }
        } else {
            if (!ins) { acc[6]  += o;  acc[7]  += 1.0f; }
            else      { acc[10] += ii; acc[11] += 1.0f; }
        }
    }

    __shared__ float red[16][12];
    const int lane = tid & 63;
    const int wave = tid >> 6;
    #pragma unroll
    for (int k = 0; k < 12; ++k) {
        float v = acc[k];
        #pragma unroll
        for (int off = 32; off > 0; off >>= 1)
            v += __shfl_down(v, off);
        acc[k] = v;
    }
    if (lane == 0) {
        #pragma unroll
        for (int k = 0; k < 12; ++k) red[wave][k] = acc[k];
    }
    __syncthreads();
    if (tid == 0) {
        float t[12];
        const int nw = nthr >> 6;
        #pragma unroll
        for (int k = 0; k < 12; ++k) {
            float s = red[0][k];
            for (int w = 1; w < nw; ++w) s += red[w][k];
            t[k] = s;
        }
        const float contactloss = CONTACT_W * (t[0] / fmaxf(t[1], 1.0f));
        const float insideloss  = INSIDE_W  * (t[2] / fmaxf(t[3], 1.0f));
        const float hand_out = t[4] / fmaxf(t[5], 1.0f) + t[6]  / fmaxf(t[7], 1.0f);
        const float hand_in  = t[8] / fmaxf(t[9], 1.0f) + t[10] / fmaxf(t[11], 1.0f);
        out[0] = contactloss + insideloss + HAND_W * (hand_out + hand_in);
    }
}

extern "C" void kernel_launch(void* const* d_in, const int* in_sizes, int n_in,
                              void* d_out, int out_size, void* d_ws, size_t ws_size,
                              hipStream_t stream) {
    const float* vertices = (const float*)d_in[0];  // [1,NV,3]
    const float* geodist  = (const float*)d_in[1];  // [NV,NV]
    const float* hand_w   = (const float*)d_in[2];  // [NHAND]
    const int*   ds       = (const int*)d_in[3];    // [NDS]
    const int*   hand_idx = (const int*)d_in[4];    // [NHAND]
    const int*   cidx     = (const int*)d_in[5];    // [NCONTACT]
    float* out = (float*)d_out;

    char* p = (char*)d_ws;
    float* hand_min = (float*)p;  p += ((NHAND * 4 + 15) & ~15);
    float* ds_min = (float*)p;    p += ((NDS * 4 + 15) & ~15);
    float* gdiq = (float*)p;      p += ((NDS * 4 + 15) & ~15);

    scan_kernel<<<BLOCKS, THREADS, SMEM_BYTES, stream>>>(
        vertices, geodist, hand_idx, ds, cidx, hand_min, ds_min, gdiq);

    finalize_kernel<<<1, 1024, 0, stream>>>(ds_min, gdiq, ds, hand_min,
                                            hand_w, hand_idx, out);
}